// Round 4
// baseline (690.139 us; speedup 1.0000x reference)
//
#include <hip/hip_runtime.h>

typedef unsigned short u16;
typedef __bf16 bf16x8 __attribute__((ext_vector_type(8)));
typedef float floatx4 __attribute__((ext_vector_type(4)));

#define B_ 2
#define L_ 2048
#define S_ 2048
#define D_ 512
#define H_ 8

static __device__ __forceinline__ u16 f2bf(float f) {
  union { float f; unsigned u; } v; v.f = f;
  unsigned u = v.u;
  return (u16)((u + 0x7FFFu + ((u >> 16) & 1u)) >> 16);  // RNE
}
static __device__ __forceinline__ float bf2f(u16 h) {
  union { unsigned u; float f; } v; v.u = ((unsigned)h) << 16;
  return v.f;
}

// async global->LDS, 16B per lane. LDS dest is wave-uniform base + lane*16.
static __device__ __forceinline__ void gload16(const void* g, void* l) {
  __builtin_amdgcn_global_load_lds(
      (const __attribute__((address_space(1))) void*)g,
      (__attribute__((address_space(3))) void*)l, 16, 0, 0);
}

// ---------------------------------------------------------------------------
// QKV projection GEMM: C[m][n] = sum_k A[m][k] * W[n][k]   (M=4096,N=512,K=512)
// z: 0 queries->qb (bf16), 1 keys->kb (bf16), 2 values->vb (bf16,+bv)
// ---------------------------------------------------------------------------
__global__ __launch_bounds__(256) void qkv_gemm(
    const float* __restrict__ Qin, const float* __restrict__ Kin, const float* __restrict__ Vin,
    const float* __restrict__ Wq, const float* __restrict__ Wk, const float* __restrict__ Wv,
    const float* __restrict__ bv,
    u16* __restrict__ qo, u16* __restrict__ ko, u16* __restrict__ vo)
{
  __shared__ u16 As[128][72];
  __shared__ u16 Bs[128][72];
  const int z = blockIdx.z;
  const float* A = (z == 0) ? Qin : (z == 1) ? Kin : Vin;
  const float* W = (z == 0) ? Wq : (z == 1) ? Wk : Wv;
  const int tid = threadIdx.x;
  const int m0 = blockIdx.y * 128;
  const int n0 = blockIdx.x * 128;
  const int lane = tid & 63, w = tid >> 6;
  const int ml = lane & 15, kl = lane >> 4;
  const int mqw = (w >> 1) * 64, nq = (w & 1) * 64;
  const int srow = tid >> 4, scg = tid & 15;

  floatx4 acc[4][4] = {};

  for (int k0 = 0; k0 < 512; k0 += 64) {
#pragma unroll
    for (int i = 0; i < 8; ++i) {
      const int r = srow + i * 16;
      float4 av = *(const float4*)&A[(size_t)(m0 + r) * 512 + k0 + scg * 4];
      ushort4 ua; ua.x = f2bf(av.x); ua.y = f2bf(av.y); ua.z = f2bf(av.z); ua.w = f2bf(av.w);
      *(ushort4*)&As[r][scg * 4] = ua;
      float4 wv = *(const float4*)&W[(size_t)(n0 + r) * 512 + k0 + scg * 4];
      ushort4 uw; uw.x = f2bf(wv.x); uw.y = f2bf(wv.y); uw.z = f2bf(wv.z); uw.w = f2bf(wv.w);
      *(ushort4*)&Bs[r][scg * 4] = uw;
    }
    __syncthreads();
#pragma unroll
    for (int kk = 0; kk < 64; kk += 32) {
      bf16x8 af[4], bfv[4];
#pragma unroll
      for (int i = 0; i < 4; ++i) af[i] = *(const bf16x8*)&As[mqw + i * 16 + ml][kk + kl * 8];
#pragma unroll
      for (int j = 0; j < 4; ++j) bfv[j] = *(const bf16x8*)&Bs[nq + j * 16 + ml][kk + kl * 8];
#pragma unroll
      for (int i = 0; i < 4; ++i)
#pragma unroll
        for (int j = 0; j < 4; ++j)
          acc[i][j] = __builtin_amdgcn_mfma_f32_16x16x32_bf16(af[i], bfv[j], acc[i][j], 0, 0, 0);
    }
    __syncthreads();
  }
#pragma unroll
  for (int i = 0; i < 4; ++i)
#pragma unroll
    for (int j = 0; j < 4; ++j) {
      const int gc = n0 + nq + j * 16 + ml;
#pragma unroll
      for (int r = 0; r < 4; ++r) {
        const int gr = m0 + mqw + i * 16 + kl * 4 + r;
        float v = acc[i][j][r];
        if (z == 0)      qo[(size_t)gr * 512 + gc] = f2bf(v);
        else if (z == 1) ko[(size_t)gr * 512 + gc] = f2bf(v);
        else             vo[(size_t)gr * 512 + gc] = f2bf(v + bv[gc]);
      }
    }
}

// ---------------------------------------------------------------------------
// mixed_q: mq[b][h][l][e] = bf16( qb[b][l][e] * mixing[h][e] )
// ---------------------------------------------------------------------------
__global__ __launch_bounds__(256) void mixq_kernel(
    const u16* __restrict__ qb, const float* __restrict__ mixing, u16* __restrict__ mq)
{
  __shared__ float mixs[8 * 512];
  const int tid = threadIdx.x;
#pragma unroll
  for (int i = 0; i < 4; ++i)
    *(float4*)&mixs[(tid + i * 256) * 4] = *(const float4*)&mixing[(tid + i * 256) * 4];
  __syncthreads();
  const size_t unit = (size_t)blockIdx.x * 256 + tid;  // one 8-elem group
  const size_t el = unit * 8;
  const int e = (int)(el & 511);
  const size_t bl = el >> 9;
  const int b = (int)(bl >> 11);
  const int l = (int)(bl & 2047);
  uint4 qv = *(const uint4*)&qb[el];
  const float q0 = bf2f((u16)(qv.x & 0xFFFFu)), q1 = bf2f((u16)(qv.x >> 16));
  const float q2 = bf2f((u16)(qv.y & 0xFFFFu)), q3 = bf2f((u16)(qv.y >> 16));
  const float q4 = bf2f((u16)(qv.z & 0xFFFFu)), q5 = bf2f((u16)(qv.z >> 16));
  const float q6 = bf2f((u16)(qv.w & 0xFFFFu)), q7 = bf2f((u16)(qv.w >> 16));
#pragma unroll
  for (int h = 0; h < 8; ++h) {
    const float* mp = &mixs[h * 512 + e];
    uint4 o;
    o.x = (unsigned)f2bf(q0 * mp[0]) | ((unsigned)f2bf(q1 * mp[1]) << 16);
    o.y = (unsigned)f2bf(q2 * mp[2]) | ((unsigned)f2bf(q3 * mp[3]) << 16);
    o.z = (unsigned)f2bf(q4 * mp[4]) | ((unsigned)f2bf(q5 * mp[5]) << 16);
    o.w = (unsigned)f2bf(q6 * mp[6]) | ((unsigned)f2bf(q7 * mp[7]) << 16);
    *(uint4*)&mq[(((size_t)b * 8 + h) * 2048 + l) * 512 + e] = o;
  }
}

// ---------------------------------------------------------------------------
// Output projection GEMM: out[m][n] = sum_k A[m][k]*Wd[n][k] + bd[n]
// DUAL=1: A = A0 + A1 (split-K partials, fallback path only)
// ---------------------------------------------------------------------------
template<int DUAL>
__global__ __launch_bounds__(256) void out_gemm(
    const float* __restrict__ A0, const float* __restrict__ A1,
    const float* __restrict__ W,
    const float* __restrict__ bias, float* __restrict__ out)
{
  __shared__ u16 As[128][72];
  __shared__ u16 Bs[128][72];
  const int tid = threadIdx.x;
  const int m0 = blockIdx.y * 128;
  const int n0 = blockIdx.x * 128;
  const int lane = tid & 63, w = tid >> 6;
  const int ml = lane & 15, kl = lane >> 4;
  const int mqw = (w >> 1) * 64, nq = (w & 1) * 64;
  const int srow = tid >> 4, scg = tid & 15;

  floatx4 acc[4][4] = {};

  for (int k0 = 0; k0 < 512; k0 += 64) {
#pragma unroll
    for (int i = 0; i < 8; ++i) {
      const int r = srow + i * 16;
      const size_t aoff = (size_t)(m0 + r) * 512 + k0 + scg * 4;
      float4 a0 = *(const float4*)&A0[aoff];
      ushort4 ua;
      if constexpr (DUAL) {
        float4 a1 = *(const float4*)&A1[aoff];
        ua.x = f2bf(a0.x + a1.x); ua.y = f2bf(a0.y + a1.y);
        ua.z = f2bf(a0.z + a1.z); ua.w = f2bf(a0.w + a1.w);
      } else {
        ua.x = f2bf(a0.x); ua.y = f2bf(a0.y); ua.z = f2bf(a0.z); ua.w = f2bf(a0.w);
      }
      *(ushort4*)&As[r][scg * 4] = ua;
      float4 wv = *(const float4*)&W[(size_t)(n0 + r) * 512 + k0 + scg * 4];
      ushort4 uw; uw.x = f2bf(wv.x); uw.y = f2bf(wv.y); uw.z = f2bf(wv.z); uw.w = f2bf(wv.w);
      *(ushort4*)&Bs[r][scg * 4] = uw;
    }
    __syncthreads();
#pragma unroll
    for (int kk = 0; kk < 64; kk += 32) {
      bf16x8 af[4], bfv[4];
#pragma unroll
      for (int i = 0; i < 4; ++i) af[i] = *(const bf16x8*)&As[mqw + i * 16 + ml][kk + kl * 8];
#pragma unroll
      for (int j = 0; j < 4; ++j) bfv[j] = *(const bf16x8*)&Bs[nq + j * 16 + ml][kk + kl * 8];
#pragma unroll
      for (int i = 0; i < 4; ++i)
#pragma unroll
        for (int j = 0; j < 4; ++j)
          acc[i][j] = __builtin_amdgcn_mfma_f32_16x16x32_bf16(af[i], bfv[j], acc[i][j], 0, 0, 0);
    }
    __syncthreads();
  }
#pragma unroll
  for (int i = 0; i < 4; ++i)
#pragma unroll
    for (int j = 0; j < 4; ++j) {
      const int gc = n0 + nq + j * 16 + ml;
#pragma unroll
      for (int r = 0; r < 4; ++r) {
        const int gr = m0 + mqw + i * 16 + kl * 4 + r;
        out[(size_t)gr * 512 + gc] = acc[i][j][r] + bias[gc];
      }
    }
}

// ---------------------------------------------------------------------------
// prep: fused cb (blocks 0..1023) + v-transpose (blocks 1024..1535)
// cb[b][h][s] = sum_d keys[b][s][d] * Wcb[h][d];  vT[b][e][s] = vb[b][s][e]
// ---------------------------------------------------------------------------
__global__ __launch_bounds__(256) void prep_kernel(
    const float* __restrict__ keys, const float* __restrict__ Wcb, float* __restrict__ cbuf,
    const u16* __restrict__ vb, u16* __restrict__ vT)
{
  __shared__ float Wl[8 * 512];   // cb weights
  __shared__ u16 t[64][72];       // transpose tile
  const int tid = threadIdx.x;
  if (blockIdx.x < 1024) {
#pragma unroll
    for (int i = 0; i < 4; ++i) {
      const int idx = tid + i * 256;
      *(float4*)&Wl[idx * 4] = *(const float4*)&Wcb[idx * 4];
    }
    __syncthreads();
    const int w = tid >> 6, lane = tid & 63;
    const int rowid = blockIdx.x * 4 + w;
    const int b = rowid >> 11, s = rowid & 2047;
    const float* kr = keys + (size_t)rowid * 512;
    float acc[8] = {0.f, 0.f, 0.f, 0.f, 0.f, 0.f, 0.f, 0.f};
    for (int e = lane; e < 512; e += 64) {
      const float kv = kr[e];
#pragma unroll
      for (int hh = 0; hh < 8; ++hh) acc[hh] += kv * Wl[hh * 512 + e];
    }
#pragma unroll
    for (int hh = 0; hh < 8; ++hh) {
#pragma unroll
      for (int off = 32; off > 0; off >>= 1) acc[hh] += __shfl_xor(acc[hh], off, 64);
    }
    if (lane == 0) {
#pragma unroll
      for (int hh = 0; hh < 8; ++hh)
        cbuf[((size_t)b * 8 + hh) * 2048 + s] = acc[hh];
    }
  } else {
    const int id = blockIdx.x - 1024;      // 0..511
    const int b = id >> 8;
    const int rem = id & 255;
    const int s0 = (rem >> 3) * 64;
    const int e0 = (rem & 7) * 64;
    const int rr = tid >> 3, g = tid & 7;
#pragma unroll
    for (int i = 0; i < 2; ++i) {
      const int r = rr + i * 32;
      *(uint4*)&t[r][g * 8] = *(const uint4*)&vb[((size_t)b * S_ + s0 + r) * 512 + e0 + g * 8];
    }
    __syncthreads();
#pragma unroll
    for (int i = 0; i < 2; ++i) {
      const int er = rr + i * 32;
      uint4 o;
      o.x = (unsigned)t[g * 8 + 0][er] | ((unsigned)t[g * 8 + 1][er] << 16);
      o.y = (unsigned)t[g * 8 + 2][er] | ((unsigned)t[g * 8 + 3][er] << 16);
      o.z = (unsigned)t[g * 8 + 4][er] | ((unsigned)t[g * 8 + 5][er] << 16);
      o.w = (unsigned)t[g * 8 + 6][er] | ((unsigned)t[g * 8 + 7][er] << 16);
      *(uint4*)&vT[((size_t)b * 512 + e0 + er) * S_ + s0 + g * 8] = o;
    }
  }
}

// ---------------------------------------------------------------------------
// Scores GEMM (per b,h): sc[l][s] = (sum_e mq[bh][l][e]*k[s][e] + cb[s]) / 8
// Staging via global_load_lds width-16 into LINEAR LDS (m97 structure).
// BF16OUT=1: bf16 scores to sb. BF16OUT=0: fp32 scores into probs region.
// ---------------------------------------------------------------------------
template<int BF16OUT>
__global__ __launch_bounds__(256) void scores_gemm(
    const u16* __restrict__ mq, const u16* __restrict__ kb,
    const float* __restrict__ cbuf, float* __restrict__ sc, u16* __restrict__ sb)
{
  __shared__ u16 As[128][64];
  __shared__ u16 Bs[128][64];
  const int tid = threadIdx.x;
  const int bh = blockIdx.z, b = bh >> 3;
  const int m0 = blockIdx.y * 128;
  const int n0 = blockIdx.x * 128;
  const u16* mqb = mq + (size_t)bh * L_ * 512;
  const u16* kbb = kb + (size_t)b * S_ * 512;
  const int lane = tid & 63, w = tid >> 6;
  const int ml = lane & 15, kl = lane >> 4;
  const int mqw = (w >> 1) * 64, nq = (w & 1) * 64;
  const int lr = lane >> 3;          // sub-row within 8-row chunk
  const int lc = (lane & 7) * 8;     // u16 col within 64

  floatx4 acc[4][4] = {};

  for (int k0 = 0; k0 < 512; k0 += 64) {
#pragma unroll
    for (int i = 0; i < 4; ++i) {
      const int c = w * 4 + i;       // 1KB chunk = 8 rows of 128B
      const int r = c * 8 + lr;
      gload16(&mqb[(size_t)(m0 + r) * 512 + k0 + lc], &As[c * 8][0]);
      gload16(&kbb[(size_t)(n0 + r) * 512 + k0 + lc], &Bs[c * 8][0]);
    }
    __syncthreads();
#pragma unroll
    for (int kk = 0; kk < 64; kk += 32) {
      bf16x8 af[4], bfv[4];
#pragma unroll
      for (int i = 0; i < 4; ++i) af[i] = *(const bf16x8*)&As[mqw + i * 16 + ml][kk + kl * 8];
#pragma unroll
      for (int j = 0; j < 4; ++j) bfv[j] = *(const bf16x8*)&Bs[nq + j * 16 + ml][kk + kl * 8];
#pragma unroll
      for (int i = 0; i < 4; ++i)
#pragma unroll
        for (int j = 0; j < 4; ++j)
          acc[i][j] = __builtin_amdgcn_mfma_f32_16x16x32_bf16(af[i], bfv[j], acc[i][j], 0, 0, 0);
    }
    __syncthreads();
  }
  if constexpr (BF16OUT) {
    u16* outp = sb + ((size_t)bh * L_ + m0) * S_ + n0;
#pragma unroll
    for (int j = 0; j < 4; ++j) {
      const int gcl = nq + j * 16 + ml;
      const float cbv = cbuf[(size_t)bh * S_ + n0 + gcl];
#pragma unroll
      for (int i = 0; i < 4; ++i)
#pragma unroll
        for (int r = 0; r < 4; ++r) {
          const int grl = mqw + i * 16 + kl * 4 + r;
          outp[(size_t)grl * S_ + gcl] = f2bf((acc[i][j][r] + cbv) * 0.125f);
        }
    }
  } else {
    float* outp = sc + ((size_t)bh * L_ + m0) * S_ + n0;
#pragma unroll
    for (int j = 0; j < 4; ++j) {
      const int gcl = nq + j * 16 + ml;
      const float cbv = cbuf[(size_t)bh * S_ + n0 + gcl];
#pragma unroll
      for (int i = 0; i < 4; ++i)
#pragma unroll
        for (int r = 0; r < 4; ++r) {
          const int grl = mqw + i * 16 + kl * 4 + r;
          outp[(size_t)grl * S_ + gcl] = (acc[i][j][r] + cbv) * 0.125f;
        }
    }
  }
}

// ---------------------------------------------------------------------------
// FUSED softmax + PV (main path). One block = 16 rows of one (b,h), full S.
// Phase 1: bf16 scores 16x2048 -> LDS via global_load_lds (64 KB).
// Phase 2: softmax; scores held in 128 VGPR/thread (16 threads/row, shfl
//          stats); write fp32 probs (coalesced) + normalized bf16 P -> LDS.
// Phase 3: PV GEMM ctx[16][64] = P[16][2048] x vT[64][2048]^T, vT streamed
//          in 8 KB chunks via global_load_lds (L2-resident per bh).
// Deletes the bf16-P HBM round-trip and the separate ctx kernel.
// ---------------------------------------------------------------------------
__global__ __launch_bounds__(256) void smctx_fused(
    const u16* __restrict__ sb, const u16* __restrict__ vT,
    float* __restrict__ probs, float* __restrict__ ctx)
{
  __shared__ u16 P[16][2048];   // 64 KB
  __shared__ u16 Bs[64][64];    //  8 KB
  const int tid = threadIdx.x;
  const int lane = tid & 63, w = tid >> 6;
  const int bh = blockIdx.y, b = bh >> 3, h = bh & 7;
  const int l0 = blockIdx.x * 16;

  // ---- phase 1: scores -> LDS (pure async DMA) ----
  const u16* srow = sb + ((size_t)bh * L_ + l0) * S_;
#pragma unroll
  for (int i = 0; i < 16; ++i) {
    const int ci = i * 4 + w;                // 1KB chunk 0..63 (uniform per wave)
    const int r = ci >> 2;                   // row 0..15
    const int cu = (ci & 3) * 512;           // u16 col of chunk start
    gload16(&srow[(size_t)r * S_ + cu + lane * 8], &P[r][cu]);
  }
  __syncthreads();

  // ---- phase 2: softmax (16 threads per row) ----
  const int row = tid >> 4, seg = tid & 15;
  const u16* prow_lds = &P[row][0];
  float e[128];
  float mx = -3.0e38f;
#pragma unroll
  for (int j = 0; j < 16; ++j) {
    const int jc = (j + seg) & 15;           // bank-rotated chunk index
    uint4 v = *(const uint4*)&prow_lds[seg * 128 + jc * 8];
    const float f0 = bf2f((u16)(v.x & 0xFFFFu)), f1 = bf2f((u16)(v.x >> 16));
    const float f2 = bf2f((u16)(v.y & 0xFFFFu)), f3 = bf2f((u16)(v.y >> 16));
    const float f4 = bf2f((u16)(v.z & 0xFFFFu)), f5 = bf2f((u16)(v.z >> 16));
    const float f6 = bf2f((u16)(v.w & 0xFFFFu)), f7 = bf2f((u16)(v.w >> 16));
    e[j * 8 + 0] = f0; e[j * 8 + 1] = f1; e[j * 8 + 2] = f2; e[j * 8 + 3] = f3;
    e[j * 8 + 4] = f4; e[j * 8 + 5] = f5; e[j * 8 + 6] = f6; e[j * 8 + 7] = f7;
    mx = fmaxf(mx, fmaxf(fmaxf(f0, f1), fmaxf(f2, f3)));
    mx = fmaxf(mx, fmaxf(fmaxf(f4, f5), fmaxf(f6, f7)));
  }
#pragma unroll
  for (int off = 8; off > 0; off >>= 1) mx = fmaxf(mx, __shfl_xor(mx, off, 64));
  float s0 = 0.f, s1 = 0.f, s2 = 0.f, s3 = 0.f;
#pragma unroll
  for (int i = 0; i < 128; i += 4) {
    e[i + 0] = __expf(e[i + 0] - mx); s0 += e[i + 0];
    e[i + 1] = __expf(e[i + 1] - mx); s1 += e[i + 1];
    e[i + 2] = __expf(e[i + 2] - mx); s2 += e[i + 2];
    e[i + 3] = __expf(e[i + 3] - mx); s3 += e[i + 3];
  }
  float sum = (s0 + s1) + (s2 + s3);
#pragma unroll
  for (int off = 8; off > 0; off >>= 1) sum += __shfl_xor(sum, off, 64);
  const float rl = 1.0f / sum;

  float* pout = probs + ((size_t)bh * L_ + l0 + row) * S_ + seg * 128;
  u16* pl = &P[row][seg * 128];
#pragma unroll
  for (int j = 0; j < 16; ++j) {
    const int jc = (j + seg) & 15;
    float p0 = e[j * 8 + 0] * rl, p1 = e[j * 8 + 1] * rl;
    float p2 = e[j * 8 + 2] * rl, p3 = e[j * 8 + 3] * rl;
    float p4 = e[j * 8 + 4] * rl, p5 = e[j * 8 + 5] * rl;
    float p6 = e[j * 8 + 6] * rl, p7 = e[j * 8 + 7] * rl;
    float4 o0; o0.x = p0; o0.y = p1; o0.z = p2; o0.w = p3;
    float4 o1; o1.x = p4; o1.y = p5; o1.z = p6; o1.w = p7;
    *(float4*)&pout[jc * 8 + 0] = o0;
    *(float4*)&pout[jc * 8 + 4] = o1;
    uint4 t;
    t.x = (unsigned)f2bf(p0) | ((unsigned)f2bf(p1) << 16);
    t.y = (unsigned)f2bf(p2) | ((unsigned)f2bf(p3) << 16);
    t.z = (unsigned)f2bf(p4) | ((unsigned)f2bf(p5) << 16);
    t.w = (unsigned)f2bf(p6) | ((unsigned)f2bf(p7) << 16);
    *(uint4*)&pl[jc * 8] = t;
  }
  __syncthreads();

  // ---- phase 3: PV GEMM ----
  const int ml = lane & 15, kl = lane >> 4;
  const u16* vrow = vT + ((size_t)b * 512 + h * 64) * S_;
  const int blr = lane >> 3;          // sub-row in 8-row chunk
  const int blc = (lane & 7) * 8;     // u16 col in 64
  floatx4 acc = {};

  for (int kc = 0; kc < 32; ++kc) {
#pragma unroll
    for (int i = 0; i < 2; ++i) {
      const int c = w * 2 + i;        // chunk 0..7 (uniform per wave)
      const int r = c * 8 + blr;      // vT e-row 0..63
      gload16(&vrow[(size_t)r * S_ + kc * 64 + blc], &Bs[c * 8][0]);
    }
    __syncthreads();
#pragma unroll
    for (int kk = 0; kk < 64; kk += 32) {
      bf16x8 a  = *(const bf16x8*)&P[ml][kc * 64 + kk + kl * 8];
      bf16x8 bb = *(const bf16x8*)&Bs[w * 16 + ml][kk + kl * 8];
      acc = __builtin_amdgcn_mfma_f32_16x16x32_bf16(a, bb, acc, 0, 0, 0);
    }
    __syncthreads();
  }
#pragma unroll
  for (int r = 0; r < 4; ++r)
    ctx[((size_t)b * L_ + l0 + kl * 4 + r) * 512 + h * 64 + w * 16 + ml] = acc[r];
}

// ---------------------------------------------------------------------------
// Fallback softmax (fp32 in place, small-ws path only)
// ---------------------------------------------------------------------------
__global__ __launch_bounds__(256) void softmax_stream_f32(float* probs)
{
  const int tid = threadIdx.x;
  const int row = blockIdx.x * 4 + (tid >> 6);
  const int lane = tid & 63;
  float s[32];
  const float* rp = probs + (size_t)row * 2048;
#pragma unroll
  for (int j = 0; j < 8; ++j) {
    float4 v = *(const float4*)&rp[lane * 4 + j * 256];
    s[4 * j + 0] = v.x; s[4 * j + 1] = v.y; s[4 * j + 2] = v.z; s[4 * j + 3] = v.w;
  }
  float m = -3.0e38f;
#pragma unroll
  for (int i = 0; i < 32; ++i) m = fmaxf(m, s[i]);
#pragma unroll
  for (int off = 32; off > 0; off >>= 1) m = fmaxf(m, __shfl_xor(m, off, 64));
  float s0 = 0.f;
#pragma unroll
  for (int i = 0; i < 32; ++i) { s[i] = __expf(s[i] - m); s0 += s[i]; }
#pragma unroll
  for (int off = 32; off > 0; off >>= 1) s0 += __shfl_xor(s0, off, 64);
  const float rl = 1.0f / s0;
  float* op = probs + (size_t)row * 2048;
#pragma unroll
  for (int j = 0; j < 8; ++j) {
    float4 o;
    o.x = s[4 * j + 0] * rl; o.y = s[4 * j + 1] * rl;
    o.z = s[4 * j + 2] * rl; o.w = s[4 * j + 3] * rl;
    *(float4*)&op[lane * 4 + j * 256] = o;
  }
}

// ---------------------------------------------------------------------------
// Fallback ctx GEMM (reads fp32 probs, split-K x2 into two partials)
// ---------------------------------------------------------------------------
__global__ __launch_bounds__(256) void ctx_gemm_f32(
    const float* __restrict__ probsf, const u16* __restrict__ vT,
    float* __restrict__ ctx0, float* __restrict__ ctx1)
{
  __shared__ u16 As[64][64];
  __shared__ u16 Bs[64][64];
  const int tid = threadIdx.x;
  const int kz = blockIdx.y;
  const int bh = blockIdx.z, b = bh >> 3, h = bh & 7;
  const int m0 = blockIdx.x * 64;
  const int lane = tid & 63, w = tid >> 6;
  const int ml = lane & 15, kl = lane >> 4;
  const int lr = lane >> 3;
  const int lc = (lane & 7) * 8;
  const u16* Bp = vT + ((size_t)b * 512 + h * 64) * S_;

  floatx4 acc[4] = {};

  const int kend = kz * 1024 + 1024;
  for (int k0 = kz * 1024; k0 < kend; k0 += 64) {
    const int srow = tid >> 4, scg = tid & 15;
#pragma unroll
    for (int i = 0; i < 4; ++i) {
      const int r = srow + i * 16;
      float4 av = *(const float4*)&probsf[((size_t)bh * L_ + m0 + r) * S_ + k0 + scg * 4];
      ushort4 ua; ua.x = f2bf(av.x); ua.y = f2bf(av.y); ua.z = f2bf(av.z); ua.w = f2bf(av.w);
      *(ushort4*)&As[r][scg * 4] = ua;
    }
#pragma unroll
    for (int i = 0; i < 2; ++i) {
      const int c = w * 2 + i;
      const int r = c * 8 + lr;
      gload16(&Bp[(size_t)r * S_ + k0 + lc], &Bs[c * 8][0]);
    }
    __syncthreads();
#pragma unroll
    for (int kk = 0; kk < 64; kk += 32) {
      bf16x8 af = *(const bf16x8*)&As[w * 16 + ml][kk + kl * 8];
#pragma unroll
      for (int j = 0; j < 4; ++j) {
        bf16x8 bfv = *(const bf16x8*)&Bs[j * 16 + ml][kk + kl * 8];
        acc[j] = __builtin_amdgcn_mfma_f32_16x16x32_bf16(af, bfv, acc[j], 0, 0, 0);
      }
    }
    __syncthreads();
  }
  float* cdst = kz ? ctx1 : ctx0;
#pragma unroll
  for (int j = 0; j < 4; ++j) {
    const int gc = h * 64 + j * 16 + ml;
#pragma unroll
    for (int r = 0; r < 4; ++r) {
      const int gl = m0 + w * 16 + kl * 4 + r;
      cdst[((size_t)b * L_ + gl) * 512 + gc] = acc[j][r];
    }
  }
}

// ---------------------------------------------------------------------------
extern "C" void kernel_launch(void* const* d_in, const int* in_sizes, int n_in,
                              void* d_out, int out_size, void* d_ws, size_t ws_size,
                              hipStream_t stream) {
  const float* queries = (const float*)d_in[0];
  const float* keys    = (const float*)d_in[1];
  const float* values  = (const float*)d_in[2];
  const float* Wq  = (const float*)d_in[4];
  const float* Wk  = (const float*)d_in[5];
  const float* Wv  = (const float*)d_in[6];
  const float* bv  = (const float*)d_in[7];
  const float* Wcb = (const float*)d_in[8];
  const float* mixing = (const float*)d_in[9];
  const float* Wd  = (const float*)d_in[10];
  const float* bd  = (const float*)d_in[11];

  float* out   = (float*)d_out;                         // [B,L,512] fp32
  float* probs = out + (size_t)B_ * L_ * 512;           // [B,H,L,S] fp32

  char* ws = (char*)d_ws;
  u16*   qb  = (u16*)(ws);                              //  4 MB  bf16 [B*L,512]
  u16*   kb  = (u16*)(ws + (size_t)4  * 1024 * 1024);   //  4 MB  bf16 [B*S,512]
  u16*   vb  = (u16*)(ws + (size_t)8  * 1024 * 1024);   //  4 MB  bf16 [B*S,512]
  u16*   vT  = (u16*)(ws + (size_t)12 * 1024 * 1024);   //  4 MB  bf16 [B,512,S]
  float* cbuf= (float*)(ws + (size_t)16 * 1024 * 1024); // 128 KB fp32 [B,H,S]
  float* ctx0= (float*)(ws + (size_t)17 * 1024 * 1024); //  8 MB  fp32 [B*L,512]
  u16*   mq  = (u16*)(ws + (size_t)25 * 1024 * 1024);   // 32 MB  bf16 [B,H,L,512]
  const size_t SB16_OFF = (size_t)57 * 1024 * 1024;
  const size_t SB16_SZ  = (size_t)B_ * H_ * L_ * S_ * 2;  // 128 MB
  u16* sb16 = (u16*)(ws + SB16_OFF);
  const bool bigws = (ws_size >= SB16_OFF + SB16_SZ + (size_t)8 * 1024 * 1024);
  float* ctx1 = bigws ? (float*)(ws + SB16_OFF + SB16_SZ)
                      : (float*)(ws + SB16_OFF);

  hipLaunchKernelGGL(qkv_gemm, dim3(4, 32, 3), dim3(256), 0, stream,
                     queries, keys, values, Wq, Wk, Wv, bv, qb, kb, vb);
  hipLaunchKernelGGL(mixq_kernel, dim3(1024), dim3(256), 0, stream, qb, mixing, mq);
  hipLaunchKernelGGL(prep_kernel, dim3(1536), dim3(256), 0, stream,
                     keys, Wcb, cbuf, vb, vT);
  if (bigws) {
    hipLaunchKernelGGL(HIP_KERNEL_NAME(scores_gemm<1>), dim3(16, 16, 16), dim3(256), 0, stream,
                       mq, kb, cbuf, probs, sb16);
    hipLaunchKernelGGL(smctx_fused, dim3(128, 16), dim3(256), 0, stream,
                       sb16, vT, probs, ctx0);
    hipLaunchKernelGGL(HIP_KERNEL_NAME(out_gemm<0>), dim3(4, 32, 1), dim3(256), 0, stream,
                       ctx0, ctx1, Wd, bd, out);
  } else {
    hipLaunchKernelGGL(HIP_KERNEL_NAME(scores_gemm<0>), dim3(16, 16, 16), dim3(256), 0, stream,
                       mq, kb, cbuf, probs, sb16);
    hipLaunchKernelGGL(softmax_stream_f32, dim3(8192), dim3(256), 0, stream, probs);
    hipLaunchKernelGGL(ctx_gemm_f32, dim3(32, 2, 16), dim3(256), 0, stream,
                       probs, vT, ctx0, ctx1);
    hipLaunchKernelGGL(HIP_KERNEL_NAME(out_gemm<1>), dim3(4, 32, 1), dim3(256), 0, stream,
                       ctx0, ctx1, Wd, bd, out);
  }
}